// Round 2
// baseline (431.570 us; speedup 1.0000x reference)
//
#include <hip/hip_runtime.h>
#include <cstdint>

typedef _Float16 f16;
typedef _Float16 f16x4 __attribute__((ext_vector_type(4)));
typedef _Float16 f16x8 __attribute__((ext_vector_type(8)));
typedef float    f32x4 __attribute__((ext_vector_type(4)));

#define MFMA(a,b,c) __builtin_amdgcn_mfma_f32_16x16x32_f16((a),(b),(c),0,0,0)

constexpr int  Bb = 8, Nn = 2048, Dd = 512, Ad = 64;
constexpr long XN = (long)Bb*Nn*Dd;   // 8388608
constexpr long WN = (long)Dd*Dd;      // 262144
constexpr long AN = (long)Bb*Nn*Ad;   // 1048576
constexpr float LO_S  = 4096.f;
constexpr float LO_INV= 1.f/4096.f;
constexpr float P_SC  = 1024.f;
constexpr float NEGF  = -3.402823466e38f;

// ---------------------------------------------------------------- prep: split fp32 -> f16 hi/lo
__global__ void prep_split(const float* __restrict__ x,
  const float* __restrict__ Wq, const float* __restrict__ Wk, const float* __restrict__ Wv,
  const float* __restrict__ aq, const float* __restrict__ ak,
  f16* __restrict__ xh, f16* __restrict__ xl, f16* __restrict__ Wh, f16* __restrict__ Wl,
  f16* __restrict__ aqh, f16* __restrict__ akh)
{
  const long total4 = (XN + 3*WN + 2*AN) >> 2;
  for (long u = blockIdx.x*(long)blockDim.x + threadIdx.x; u < total4;
       u += (long)gridDim.x*blockDim.x) {
    long i = u << 2;
    if (i < XN) {
      float4 v = *(const float4*)(x + i);
      float vv[4] = {v.x, v.y, v.z, v.w};
      f16x4 h, l;
      #pragma unroll
      for (int t=0;t<4;++t){ f16 hh=(f16)vv[t]; h[t]=hh; l[t]=(f16)((vv[t]-(float)hh)*LO_S); }
      *(f16x4*)(xh+i)=h; *(f16x4*)(xl+i)=l;
    } else if (i < XN + 3*WN) {
      long j = i - XN;
      const float* w = (j < WN) ? (Wq + j) : (j < 2*WN ? (Wk + (j-WN)) : (Wv + (j-2*WN)));
      float4 v = *(const float4*)w;
      float vv[4] = {v.x, v.y, v.z, v.w};
      f16x4 h, l;
      #pragma unroll
      for (int t=0;t<4;++t){ f16 hh=(f16)vv[t]; h[t]=hh; l[t]=(f16)((vv[t]-(float)hh)*LO_S); }
      *(f16x4*)(Wh+j)=h; *(f16x4*)(Wl+j)=l;
    } else {
      long j = i - XN - 3*WN;
      const float* s = (j < AN) ? (aq + j) : (ak + (j-AN));
      f16*         d = (j < AN) ? (aqh + j) : (akh + (j-AN));
      float4 v = *(const float4*)s;
      float vv[4] = {v.x, v.y, v.z, v.w};
      f16x4 h;
      #pragma unroll
      for (int t=0;t<4;++t) h[t]=(f16)vv[t];
      *(f16x4*)d = h;
    }
  }
}

// ---------------------------------------------------------------- q,k projection: 3-pass split GEMM
// D[e][xrow] = sum_d W[e,d]*x[row,d]; A = W rows (i=e), B = x rows (j=row). Both K-major.
__global__ __launch_bounds__(256, 2) void proj_qk(
  const f16* __restrict__ xh, const f16* __restrict__ xl,
  const f16* __restrict__ Wh, const f16* __restrict__ Wl,
  const float* __restrict__ bq, const float* __restrict__ bk,
  f16* __restrict__ qh, f16* __restrict__ ql,
  f16* __restrict__ kh, f16* __restrict__ kl)
{
  const int z = blockIdx.z;
  const f16* Whz = Wh + (long)z*WN;
  const f16* Wlz = Wl + (long)z*WN;
  const float* bias = z ? bk : bq;
  f16* oh = z ? kh : qh;
  f16* ol = z ? kl : ql;
  const int e0 = blockIdx.x*128, m0 = blockIdx.y*128;
  __shared__ f16 Ah[128][40], Al[128][40], Bh[128][40], Bl[128][40];
  const int tid = threadIdx.x, lane = tid & 63, wid = tid >> 6;
  const int wi = wid & 1, wj = wid >> 1;
  const int r16 = lane & 15, g16 = lane >> 4;

  f32x4 acch[4][4], accl[4][4];
  #pragma unroll
  for (int a=0;a<4;++a)
    #pragma unroll
    for (int bI=0;bI<4;++bI){ acch[a][bI]=(f32x4){0.f,0.f,0.f,0.f}; accl[a][bI]=(f32x4){0.f,0.f,0.f,0.f}; }

  f16x8 st[8];
  #pragma unroll
  for (int t=0;t<2;++t) {
    int u = tid + t*256; int row = u>>2, sg = u&3;
    long ko = (long)sg*8;
    st[t*4+0] = *(const f16x8*)&Whz[(long)(e0+row)*Dd + ko];
    st[t*4+1] = *(const f16x8*)&Wlz[(long)(e0+row)*Dd + ko];
    st[t*4+2] = *(const f16x8*)&xh [(long)(m0+row)*Dd + ko];
    st[t*4+3] = *(const f16x8*)&xl [(long)(m0+row)*Dd + ko];
  }
  for (int kt=0; kt<16; ++kt) {
    __syncthreads();
    #pragma unroll
    for (int t=0;t<2;++t) {
      int u = tid + t*256; int row = u>>2, sg = u&3;
      *(f16x8*)&Ah[row][sg*8] = st[t*4+0];
      *(f16x8*)&Al[row][sg*8] = st[t*4+1];
      *(f16x8*)&Bh[row][sg*8] = st[t*4+2];
      *(f16x8*)&Bl[row][sg*8] = st[t*4+3];
    }
    __syncthreads();
    if (kt < 15) {
      #pragma unroll
      for (int t=0;t<2;++t) {
        int u = tid + t*256; int row = u>>2, sg = u&3;
        long ko = (long)(kt+1)*32 + sg*8;
        st[t*4+0] = *(const f16x8*)&Whz[(long)(e0+row)*Dd + ko];
        st[t*4+1] = *(const f16x8*)&Wlz[(long)(e0+row)*Dd + ko];
        st[t*4+2] = *(const f16x8*)&xh [(long)(m0+row)*Dd + ko];
        st[t*4+3] = *(const f16x8*)&xl [(long)(m0+row)*Dd + ko];
      }
    }
    f16x8 ahf[4], alf[4];
    #pragma unroll
    for (int fi=0;fi<4;++fi) {
      ahf[fi] = *(const f16x8*)&Ah[wi*64 + fi*16 + r16][g16*8];
      alf[fi] = *(const f16x8*)&Al[wi*64 + fi*16 + r16][g16*8];
    }
    #pragma unroll
    for (int fj=0;fj<4;++fj) {
      f16x8 bhf = *(const f16x8*)&Bh[wj*64 + fj*16 + r16][g16*8];
      f16x8 blf = *(const f16x8*)&Bl[wj*64 + fj*16 + r16][g16*8];
      #pragma unroll
      for (int fi=0;fi<4;++fi) {
        acch[fi][fj] = MFMA(ahf[fi], bhf, acch[fi][fj]);
        accl[fi][fj] = MFMA(ahf[fi], blf, accl[fi][fj]);
        accl[fi][fj] = MFMA(alf[fi], bhf, accl[fi][fj]);
      }
    }
  }
  #pragma unroll
  for (int fi=0;fi<4;++fi) {
    const int eb = e0 + wi*64 + fi*16 + g16*4;
    const float4 b4 = *(const float4*)&bias[eb];
    const float bbv[4] = {b4.x, b4.y, b4.z, b4.w};
    #pragma unroll
    for (int fj=0;fj<4;++fj) {
      const int xr = m0 + wj*64 + fj*16 + r16;
      f16x4 h4, l4;
      #pragma unroll
      for (int rg=0;rg<4;++rg) {
        float v = acch[fi][fj][rg] + accl[fi][fj][rg]*LO_INV + bbv[rg];
        f16 hh = (f16)v;
        h4[rg] = hh;
        l4[rg] = (f16)((v - (float)hh)*LO_S);
      }
      *(f16x4*)&oh[(long)xr*Dd + eb] = h4;
      *(f16x4*)&ol[(long)xr*Dd + eb] = l4;
    }
  }
}

// ---------------------------------------------------------------- v projection (1-pass), writes vT[b][e][n]
// D[xrow][e]: A = x rows (i=xrow), B = Wv rows (j=e)
__global__ __launch_bounds__(256, 2) void proj_v(
  const f16* __restrict__ xh, const f16* __restrict__ Wvh,
  const float* __restrict__ bv, f16* __restrict__ vT)
{
  const int e0 = blockIdx.x*128, m0 = blockIdx.y*128;
  __shared__ f16 Ax[128][40], Bw[128][40];
  const int tid = threadIdx.x, lane = tid & 63, wid = tid >> 6;
  const int wi = wid & 1, wj = wid >> 1;
  const int r16 = lane & 15, g16 = lane >> 4;

  f32x4 acc[4][4];
  #pragma unroll
  for (int a=0;a<4;++a)
    #pragma unroll
    for (int bI=0;bI<4;++bI) acc[a][bI]=(f32x4){0.f,0.f,0.f,0.f};

  f16x8 st[4];
  #pragma unroll
  for (int t=0;t<2;++t) {
    int u = tid + t*256; int row = u>>2, sg = u&3;
    st[t*2+0] = *(const f16x8*)&xh [(long)(m0+row)*Dd + sg*8];
    st[t*2+1] = *(const f16x8*)&Wvh[(long)(e0+row)*Dd + sg*8];
  }
  for (int kt=0; kt<16; ++kt) {
    __syncthreads();
    #pragma unroll
    for (int t=0;t<2;++t) {
      int u = tid + t*256; int row = u>>2, sg = u&3;
      *(f16x8*)&Ax[row][sg*8] = st[t*2+0];
      *(f16x8*)&Bw[row][sg*8] = st[t*2+1];
    }
    __syncthreads();
    if (kt < 15) {
      #pragma unroll
      for (int t=0;t<2;++t) {
        int u = tid + t*256; int row = u>>2, sg = u&3;
        long ko = (long)(kt+1)*32 + sg*8;
        st[t*2+0] = *(const f16x8*)&xh [(long)(m0+row)*Dd + ko];
        st[t*2+1] = *(const f16x8*)&Wvh[(long)(e0+row)*Dd + ko];
      }
    }
    f16x8 af[4];
    #pragma unroll
    for (int fi=0;fi<4;++fi) af[fi] = *(const f16x8*)&Ax[wi*64 + fi*16 + r16][g16*8];
    #pragma unroll
    for (int fj=0;fj<4;++fj) {
      f16x8 bf = *(const f16x8*)&Bw[wj*64 + fj*16 + r16][g16*8];
      #pragma unroll
      for (int fi=0;fi<4;++fi) acc[fi][fj] = MFMA(af[fi], bf, acc[fi][fj]);
    }
  }
  #pragma unroll
  for (int fj=0;fj<4;++fj) {
    const int e = e0 + wj*64 + fj*16 + r16;
    const float bve = bv[e];
    #pragma unroll
    for (int fi=0;fi<4;++fi) {
      const int xr0 = m0 + wi*64 + fi*16 + g16*4;
      const int bbi = xr0 >> 11, nn = xr0 & 2047;
      f16x4 h4;
      #pragma unroll
      for (int rg=0;rg<4;++rg) h4[rg] = (f16)(acc[fi][fj][rg] + bve);
      *(f16x4*)&vT[((long)bbi*Dd + e)*Nn + nn] = h4;
    }
  }
}

// ---------------------------------------------------------------- fused flash attention
// LDS layout (dynamic, 121856 B)
constexpr int FLASH_LDS = 121856;

__global__ __launch_bounds__(512, 2) void flash(
  const f16* __restrict__ qhg, const f16* __restrict__ qlg,
  const f16* __restrict__ khg, const f16* __restrict__ klg,
  const f16* __restrict__ vT,  const f16* __restrict__ aqg, const f16* __restrict__ akg,
  const int* __restrict__ adj, const float* __restrict__ mcp, const float* __restrict__ thp,
  float* __restrict__ out)
{
  extern __shared__ char smem[];
  f16 (* __restrict__ QL)[520] = (f16(*)[520])(smem);            // 66560
  f16 (* __restrict__ KH)[136] = (f16(*)[136])(smem + 66560);    // 17408
  f16 (* __restrict__ KL)[136] = (f16(*)[136])(smem + 83968);    // 17408
  f16 (* __restrict__ AK)[72]  = (f16(*)[72]) (smem + 101376);   // 9216
  f16 (* __restrict__ PS)[72]  = (f16(*)[72]) (smem + 110592);   // 9216
  float* pmax = (float*)(smem + 119808);  // [2][64]
  float* psum = (float*)(smem + 120320);  // [2][64]
  float* mnew = (float*)(smem + 120832);  // [64]
  float* scl  = (float*)(smem + 121088);  // [64]
  float* mst  = (float*)(smem + 121344);  // [64]
  float* lst  = (float*)(smem + 121600);  // [64]

  const int b  = blockIdx.y;
  const int r0 = blockIdx.x * 64;
  const int tid = threadIdx.x;
  const int lane = tid & 63, wid = tid >> 6;
  const int wm = wid & 3, wn = wid >> 2;
  const int r16 = lane & 15, g16 = lane >> 4;
  const float cc = mcp[0], thr = thp[0];

  if (tid < 64) { mst[tid] = NEGF; lst[tid] = 0.f; }

  const long qbase = ((long)(b*Nn + r0))*Dd;
  for (int u = tid; u < 64*Dd/8; u += 512) {
    int row = u >> 6, sg = u & 63;
    *(f16x8*)&QL[row][sg*8] = *(const f16x8*)&qlg[qbase + (long)row*Dd + sg*8];
  }
  f16x8 qhr[16];
  {
    const f16* qrow = qhg + qbase + (long)(wm*16 + r16)*Dd;
    #pragma unroll
    for (int ks=0; ks<16; ++ks) qhr[ks] = *(const f16x8*)&qrow[ks*32 + g16*8];
  }
  f16x8 aqr[2];
  {
    const f16* arow = aqg + ((long)(b*Nn + r0 + wm*16 + r16))*Ad;
    aqr[0] = *(const f16x8*)&arow[g16*8];
    aqr[1] = *(const f16x8*)&arow[32 + g16*8];
  }
  f32x4 oacc[4][4];
  #pragma unroll
  for (int i=0;i<4;++i)
    #pragma unroll
    for (int j=0;j<4;++j) oacc[i][j] = (f32x4){0.f,0.f,0.f,0.f};

  __syncthreads();

  for (int ct=0; ct<Nn/64; ++ct) {
    const int cb = ct*64;
    int adjv[2][4];
    {
      const int* ap = adj + ((long)(b*Nn + r0 + wm*16))*Nn + cb + wn*32 + r16;
      #pragma unroll
      for (int nf=0; nf<2; ++nf)
        #pragma unroll
        for (int rg=0; rg<4; ++rg)
          adjv[nf][rg] = ap[(long)(g16*4+rg)*Nn + nf*16];
    }
    f32x4 sacc[2], slo[2], aacc[2];
    #pragma unroll
    for (int nf=0;nf<2;++nf){ sacc[nf]=(f32x4){0.f,0.f,0.f,0.f}; slo[nf]=(f32x4){0.f,0.f,0.f,0.f}; aacc[nf]=(f32x4){0.f,0.f,0.f,0.f}; }

    for (int kc=0; kc<4; ++kc) {
      __syncthreads();
      {
        const long gb = ((long)(b*Nn + cb))*Dd + kc*128;
        const int ua = tid, ub = tid + 512;
        const int ra = ua>>4, sa = ua&15, rb = ub>>4, sb = ub&15;
        f16x8 h0 = *(const f16x8*)&khg[gb + (long)ra*Dd + sa*8];
        f16x8 h1 = *(const f16x8*)&khg[gb + (long)rb*Dd + sb*8];
        f16x8 l0 = *(const f16x8*)&klg[gb + (long)ra*Dd + sa*8];
        f16x8 l1 = *(const f16x8*)&klg[gb + (long)rb*Dd + sb*8];
        *(f16x8*)&KH[ra][sa*8] = h0;
        *(f16x8*)&KH[rb][sb*8] = h1;
        *(f16x8*)&KL[ra][sa*8] = l0;
        *(f16x8*)&KL[rb][sb*8] = l1;
        if (kc == 3) {
          int rr = tid>>3, sg = tid&7;
          *(f16x8*)&AK[rr][sg*8] = *(const f16x8*)&akg[((long)(b*Nn + cb))*Ad + (long)rr*Ad + sg*8];
        }
      }
      __syncthreads();
      #pragma unroll
      for (int k4=0; k4<4; ++k4) {
        const int ks = kc*4 + k4;
        f16x8 alo = *(const f16x8*)&QL[wm*16 + r16][ks*32 + g16*8];
        #pragma unroll
        for (int nf=0; nf<2; ++nf) {
          const int cr = wn*32 + nf*16 + r16;
          f16x8 bh = *(const f16x8*)&KH[cr][k4*32 + g16*8];
          f16x8 bl = *(const f16x8*)&KL[cr][k4*32 + g16*8];
          sacc[nf] = MFMA(qhr[ks], bh, sacc[nf]);
          slo[nf]  = MFMA(qhr[ks], bl, slo[nf]);
          slo[nf]  = MFMA(alo,     bh, slo[nf]);
        }
      }
    }
    #pragma unroll
    for (int ks=0; ks<2; ++ks)
      #pragma unroll
      for (int nf=0; nf<2; ++nf) {
        f16x8 bf = *(const f16x8*)&AK[wn*32 + nf*16 + r16][ks*32 + g16*8];
        aacc[nf] = MFMA(aqr[ks], bf, aacc[nf]);
      }
    // elementwise merge + adjacency mask
    float sv[2][4], mx[4];
    #pragma unroll
    for (int rg=0; rg<4; ++rg) {
      #pragma unroll
      for (int nf=0; nf<2; ++nf) {
        float s = (sacc[nf][rg] + slo[nf][rg]*LO_INV) / 22.627416997969522f;
        float a = aacc[nf][rg] * 0.125f;
        float m = (1.f - cc)*s + cc*a;
        s = ((a != 0.f) && (s > thr)) ? m : s;
        sv[nf][rg] = adjv[nf][rg] ? s : NEGF;
      }
      mx[rg] = fmaxf(sv[0][rg], sv[1][rg]);
    }
    #pragma unroll
    for (int off=1; off<16; off<<=1)
      #pragma unroll
      for (int rg=0; rg<4; ++rg)
        mx[rg] = fmaxf(mx[rg], __shfl_xor(mx[rg], off));
    if (r16 == 0) {
      #pragma unroll
      for (int rg=0; rg<4; ++rg) pmax[wn*64 + wm*16 + g16*4 + rg] = mx[rg];
    }
    __syncthreads();
    if (tid < 64) {
      float tmax = fmaxf(pmax[tid], pmax[64+tid]);
      float mo = mst[tid];
      float mn = fmaxf(mo, tmax);
      mnew[tid] = mn;
      scl[tid]  = expf(mo - mn);
      mst[tid]  = mn;
    }
    __syncthreads();
    float sm[4];
    #pragma unroll
    for (int rg=0; rg<4; ++rg) {
      const int rr = wm*16 + g16*4 + rg;
      const float mn = mnew[rr];
      float p0 = expf(sv[0][rg] - mn);
      float p1 = expf(sv[1][rg] - mn);
      PS[rr][wn*32 + r16]      = (f16)(p0 * P_SC);
      PS[rr][wn*32 + 16 + r16] = (f16)(p1 * P_SC);
      sm[rg] = p0 + p1;
    }
    #pragma unroll
    for (int off=1; off<16; off<<=1)
      #pragma unroll
      for (int rg=0; rg<4; ++rg)
        sm[rg] += __shfl_xor(sm[rg], off);
    if (r16 == 0) {
      #pragma unroll
      for (int rg=0; rg<4; ++rg) psum[wn*64 + wm*16 + g16*4 + rg] = sm[rg];
    }
    __syncthreads();
    if (tid < 64) lst[tid] = lst[tid]*scl[tid] + psum[tid] + psum[64+tid];
    // PV: O^T[d][r] += sum_c vT[d][c] * P[r][c]
    float scj[4];
    #pragma unroll
    for (int j=0;j<4;++j) scj[j] = scl[j*16 + r16];
    #pragma unroll
    for (int i=0;i<4;++i)
      #pragma unroll
      for (int j=0;j<4;++j)
        #pragma unroll
        for (int rg=0;rg<4;++rg) oacc[i][j][rg] *= scj[j];
    #pragma unroll
    for (int ks=0; ks<2; ++ks) {
      f16x8 va[4];
      const f16* vb = vT + ((long)(b*Dd) + wid*64 + r16)*Nn + cb + ks*32 + g16*8;
      #pragma unroll
      for (int i=0;i<4;++i) va[i] = *(const f16x8*)&vb[(long)i*16*Nn];
      #pragma unroll
      for (int j=0;j<4;++j) {
        f16x8 pb = *(const f16x8*)&PS[j*16 + r16][ks*32 + g16*8];
        #pragma unroll
        for (int i=0;i<4;++i) oacc[i][j] = MFMA(va[i], pb, oacc[i][j]);
      }
    }
  }
  __syncthreads();
  const long ob = ((long)(b*Nn + r0))*Dd;
  #pragma unroll
  for (int j=0;j<4;++j) {
    const int rr = j*16 + r16;
    const float li = 1.f / (lst[rr] * P_SC);
    #pragma unroll
    for (int i=0;i<4;++i) {
      f32x4 v;
      #pragma unroll
      for (int rg=0;rg<4;++rg) v[rg] = oacc[i][j][rg] * li;
      *(f32x4*)&out[ob + (long)rr*Dd + wid*64 + i*16 + g16*4] = v;
    }
  }
}

// ---------------------------------------------------------------- launch
extern "C" void kernel_launch(void* const* d_in, const int* in_sizes, int n_in,
                              void* d_out, int out_size, void* d_ws, size_t ws_size,
                              hipStream_t stream)
{
  const float* x   = (const float*)d_in[0];
  const float* qa  = (const float*)d_in[1];
  const float* ka  = (const float*)d_in[2];
  const int*   adj = (const int*)  d_in[3];
  const float* mc  = (const float*)d_in[4];
  const float* Wq  = (const float*)d_in[5];
  const float* bq  = (const float*)d_in[6];
  const float* Wk  = (const float*)d_in[7];
  const float* bk  = (const float*)d_in[8];
  const float* Wv  = (const float*)d_in[9];
  const float* bv  = (const float*)d_in[10];
  const float* th  = (const float*)d_in[11];
  float* out = (float*)d_out;

  f16* p  = (f16*)d_ws;
  f16* xh = p;  p += XN;
  f16* xl = p;  p += XN;
  f16* Wh = p;  p += 3*WN;
  f16* Wl = p;  p += 3*WN;
  f16* qh = p;  p += XN;
  f16* ql = p;  p += XN;
  f16* kh = p;  p += XN;
  f16* kl = p;  p += XN;
  f16* vT = p;  p += XN;
  f16* aqh = p; p += AN;
  f16* akh = p; p += AN;

  prep_split<<<dim3(2048), dim3(256), 0, stream>>>(x, Wq, Wk, Wv, qa, ka,
                                                   xh, xl, Wh, Wl, aqh, akh);
  proj_qk<<<dim3(4,128,2), dim3(256), 0, stream>>>(xh, xl, Wh, Wl, bq, bk,
                                                   qh, ql, kh, kl);
  proj_v<<<dim3(4,128), dim3(256), 0, stream>>>(xh, Wh + 2*WN, bv, vT);

  hipFuncSetAttribute(reinterpret_cast<const void*>(flash),
                      hipFuncAttributeMaxDynamicSharedMemorySize, FLASH_LDS);
  flash<<<dim3(Nn/64, Bb), dim3(512), FLASH_LDS, stream>>>(qh, ql, kh, kl, vT,
                                                           aqh, akh, adj, mc, th, out);
}